// Round 1
// baseline (535.210 us; speedup 1.0000x reference)
//
#include <hip/hip_runtime.h>

// Conv1dFFTInt8: B=16, CIN=128, COUT=128, L=4096, out_size==1.
// Identity: ifft(sum_l X[l]W[l])[0] = sum_n x[n] * w[(L-n) mod L]  (real inputs)
// => out[b,o] = bias[o] + sum_i sum_m w[o,i,m] * x[b,i,(L-m)&(L-1)]
//
// Roofline: weight 268 MB read once (HBM) + x 32 MB  => ~46 us @ 6.3 TB/s.
// This version: o-tile 32 / one ci per block (x read once per block, 128 MB
// total L2-side), global_load_lds staging with per-lane reversed source,
// double-buffered LDS with one barrier per chunk.

constexpr int LEN   = 4096;
constexpr int CIN_  = 128;
constexpr int COUT_ = 128;
constexpr int BATCH = 16;

__global__ void init_out_kernel(const float* __restrict__ bias, float* __restrict__ out) {
    int t = blockIdx.x * 256 + threadIdx.x;
    if (t < BATCH * COUT_) out[t] = bias[t & (COUT_ - 1)];
}

// Async 4B global->LDS. LDS dest is wave-uniform base; HW writes base+lane*4.
// The reversal lives in the per-lane GLOBAL address (supported), LDS stays linear.
__device__ __forceinline__ void gload_lds4(const float* g, float* l) {
    __builtin_amdgcn_global_load_lds(
        (const __attribute__((address_space(1))) unsigned int*)g,
        (__attribute__((address_space(3))) unsigned int*)l, 4, 0, 0);
}

// Wave wv stages b in [4wv,4wv+4): lds[b][mm] = x[b,ci,(LEN-m0-mm)&4095], mm in [0,512)
__device__ __forceinline__ void stage_chunk(const float* __restrict__ x, float* dst_base,
                                            int ci, int m0, int wv, int lane) {
#pragma unroll
    for (int bb = 0; bb < 4; ++bb) {
        const int b = 4 * wv + bb;
        const float* xc = x + ((b * CIN_ + ci) << 12);
        float* dstb = dst_base + (b << 9);
#pragma unroll
        for (int t = 0; t < 8; ++t) {
            const int n = (LEN - m0 - (t << 6) - lane) & (LEN - 1);  // per-lane reversed src
            gload_lds4(xc + n, dstb + (t << 6));
        }
    }
}

// Block: 256 threads = 4 waves. Each block: 32 o-rows (8/wave), ONE input
// channel ci, 8 K-chunks of 512. Grid = 4 o-tiles * 128 channels = 512 blocks,
// 2 blocks/CU. bk%8 == ci%8 keeps the 4 channel-sharing blocks on one XCD.
__global__ __launch_bounds__(256, 2)
void conv_fft_dot_kernel(const float* __restrict__ x, const float* __restrict__ w,
                         float* __restrict__ out) {
    // 69,632 B: x double-buffer = 2*8192 floats; reduce area (256 rows * 68) reuses all.
    __shared__ float lds[17408];

    const int tid   = threadIdx.x;
    const int lane  = tid & 63;
    const int wv    = __builtin_amdgcn_readfirstlane(tid >> 6);  // provably uniform
    const int bk    = blockIdx.x;
    const int ot    = bk >> 7;     // 0..3
    const int ci    = bk & 127;    // input channel
    const int obase = ot * 32 + wv * 8;

    float acc[16][8];
#pragma unroll
    for (int b = 0; b < 16; ++b)
#pragma unroll
        for (int j = 0; j < 8; ++j) acc[b][j] = 0.f;

    stage_chunk(x, lds, ci, 0, wv, lane);
    __syncthreads();

#pragma unroll 1
    for (int q = 0; q < 8; ++q) {
        const int m0 = q << 9;
        const float4* __restrict__ xb = (const float4*)(lds + ((q & 1) << 13));

        // ---- weight stream first: 16 dwordx4 in flight per wave (16 KB)
        float4 w0[8], w1[8];
#pragma unroll
        for (int j = 0; j < 8; ++j) {
            const float4* wp = (const float4*)(w + (((obase + j) * CIN_ + ci) << 12) + m0);
            w0[j] = wp[lane];
            w1[j] = wp[64 + lane];
        }

        // ---- issue next chunk's x staging early; completes under the FMAs
        if (q < 7)
            stage_chunk(x, lds + (((q + 1) & 1) << 13), ci, (q + 1) << 9, wv, lane);

        // ---- compute: 32 FMAs per ds_read_b128
#pragma unroll
        for (int b = 0; b < 16; ++b) {
            const float4 xv = xb[(b << 7) + lane];
#pragma unroll
            for (int j = 0; j < 8; ++j) {
                acc[b][j] += xv.x * w0[j].x;
                acc[b][j] += xv.y * w0[j].y;
                acc[b][j] += xv.z * w0[j].z;
                acc[b][j] += xv.w * w0[j].w;
            }
        }
#pragma unroll
        for (int b = 0; b < 16; ++b) {
            const float4 xv = xb[(b << 7) + 64 + lane];
#pragma unroll
            for (int j = 0; j < 8; ++j) {
                acc[b][j] += xv.x * w1[j].x;
                acc[b][j] += xv.y * w1[j].y;
                acc[b][j] += xv.z * w1[j].z;
                acc[b][j] += xv.w * w1[j].w;
            }
        }
        __syncthreads();  // stage loads are ~4K cycles old: drain is free
    }

    // ---- cross-lane reduction via padded LDS transpose, 2 passes (8 o per wave)
#pragma unroll 1
    for (int pass = 0; pass < 2; ++pass) {
        if (pass) __syncthreads();
#pragma unroll
        for (int b = 0; b < 16; ++b)
#pragma unroll
            for (int jj = 0; jj < 4; ++jj)
                lds[(wv * 64 + b * 4 + jj) * 68 + lane] = acc[b][pass * 4 + jj];
        __syncthreads();
        {
            const int st = tid & 63;
            const float4* row = (const float4*)(lds + (wv * 64 + st) * 68);
            float sum = 0.f;
#pragma unroll
            for (int l = 0; l < 16; ++l) {
                const float4 v = row[l];
                sum += v.x + v.y + v.z + v.w;
            }
            const int b = st >> 2, jj = st & 3;
            const int o = obase + pass * 4 + jj;
            atomicAdd(out + b * COUT_ + o, sum);
        }
    }
}

extern "C" void kernel_launch(void* const* d_in, const int* in_sizes, int n_in,
                              void* d_out, int out_size, void* d_ws, size_t ws_size,
                              hipStream_t stream) {
    const float* x    = (const float*)d_in[0];   // [16,128,4096]
    const float* wgt  = (const float*)d_in[1];   // [128,128,4096]
    const float* bias = (const float*)d_in[2];   // [128]
    float* out = (float*)d_out;                  // [16,128,1]
    (void)in_sizes; (void)n_in; (void)d_ws; (void)ws_size; (void)out_size;

    init_out_kernel<<<8, 256, 0, stream>>>(bias, out);
    conv_fft_dot_kernel<<<512, 256, 0, stream>>>(x, wgt, out);
}

// Round 2
// 497.868 us; speedup vs baseline: 1.0750x; 1.0750x over previous
//
#include <hip/hip_runtime.h>

// Conv1dFFTInt8: B=16, CIN=128, COUT=128, L=4096, out_size==1.
// Identity: ifft(sum_l X[l]W[l])[0] = sum_n x[n] * w[(L-n) mod L]  (real inputs)
// => out[b,o] = bias[o] + sum_i sum_m w[o,i,m] * x[b,i,(L-m)&(L-1)]
//
// Roofline: weight 268 MB read once (HBM) + x ~128 MB L2/L3-side => ~63 us.
// Round-1 failure: acc[16][8]+w[16] = 200 live VGPRs -> massive scratch spill
// (943 MB WRITE_SIZE). Fix: 512-thread blocks (8 waves, 4 o-rows per wave),
// acc[16][4]=64 VGPR + w 32 VGPR, __launch_bounds__(512,4) caps at 128 VGPR,
// 2 blocks/CU. Same traffic structure as round 1, no spill.

constexpr int LEN   = 4096;
constexpr int CIN_  = 128;
constexpr int COUT_ = 128;
constexpr int BATCH = 16;

__global__ void init_out_kernel(const float* __restrict__ bias, float* __restrict__ out) {
    int t = blockIdx.x * 256 + threadIdx.x;
    if (t < BATCH * COUT_) out[t] = bias[t & (COUT_ - 1)];
}

// Async 4B global->LDS. LDS dest is wave-uniform base; HW writes base+lane*4.
// The index reversal lives in the per-lane GLOBAL address; LDS stays linear.
__device__ __forceinline__ void gload_lds4(const float* g, float* l) {
    __builtin_amdgcn_global_load_lds(
        (const __attribute__((address_space(1))) unsigned int*)g,
        (__attribute__((address_space(3))) unsigned int*)l, 4, 0, 0);
}

// Wave wv stages batches {2wv, 2wv+1}: lds[b][mm] = x[b,ci,(LEN-m0-mm)&4095], mm in [0,512)
__device__ __forceinline__ void stage_chunk(const float* __restrict__ x, float* dst_base,
                                            int ci, int m0, int wv, int lane) {
#pragma unroll
    for (int bb = 0; bb < 2; ++bb) {
        const int b = 2 * wv + bb;
        const float* xc = x + ((b * CIN_ + ci) << 12);
        float* dstb = dst_base + (b << 9);
#pragma unroll
        for (int t = 0; t < 8; ++t) {
            const int n = (LEN - m0 - (t << 6) - lane) & (LEN - 1);  // reversed source
            gload_lds4(xc + n, dstb + (t << 6));
        }
    }
}

// Block: 512 threads = 8 waves, each wave 4 o-rows (32 per block), ONE input
// channel. 8 K-chunks of 512. Grid = 4 o-tiles * 128 channels = 512 blocks.
// bk%8 == ci%8: the 4 channel-sharing blocks land on one XCD (x L2-hits).
__global__ __launch_bounds__(512, 4)
void conv_fft_dot_kernel(const float* __restrict__ x, const float* __restrict__ w,
                         float* __restrict__ out) {
    // 69,632 B: x double-buffer = 2*8192 floats (64 KB); reduce area 256 rows * 68.
    __shared__ float lds[17408];

    const int tid   = threadIdx.x;
    const int lane  = tid & 63;
    const int wv    = __builtin_amdgcn_readfirstlane(tid >> 6);
    const int bk    = blockIdx.x;
    const int ot    = bk >> 7;     // 0..3
    const int ci    = bk & 127;    // input channel
    const int obase = ot * 32 + wv * 4;

    float acc[16][4];
#pragma unroll
    for (int b = 0; b < 16; ++b)
#pragma unroll
        for (int j = 0; j < 4; ++j) acc[b][j] = 0.f;

    stage_chunk(x, lds, ci, 0, wv, lane);
    __syncthreads();

#pragma unroll 1
    for (int q = 0; q < 8; ++q) {
        const int m0 = q << 9;
        const float4* __restrict__ xb = (const float4*)(lds + ((q & 1) << 13));

        // ---- weight stream first (oldest in vmcnt queue): 8 dwordx4 / lane
        float4 wA[4], wB[4];
#pragma unroll
        for (int j = 0; j < 4; ++j) {
            const float4* wp = (const float4*)(w + (((obase + j) * CIN_ + ci) << 12) + m0);
            wA[j] = wp[lane];
            wB[j] = wp[64 + lane];
        }

        // ---- issue next chunk's x staging; completes under the FMAs
        if (q < 7)
            stage_chunk(x, lds + (((q + 1) & 1) << 13), ci, (q + 1) << 9, wv, lane);

        // ---- compute: 16 FMAs per ds_read_b128
#pragma unroll
        for (int b = 0; b < 16; ++b) {
            const float4 xv = xb[(b << 7) + lane];
#pragma unroll
            for (int j = 0; j < 4; ++j) {
                acc[b][j] += xv.x * wA[j].x;
                acc[b][j] += xv.y * wA[j].y;
                acc[b][j] += xv.z * wA[j].z;
                acc[b][j] += xv.w * wA[j].w;
            }
        }
#pragma unroll
        for (int b = 0; b < 16; ++b) {
            const float4 xv = xb[(b << 7) + 64 + lane];
#pragma unroll
            for (int j = 0; j < 4; ++j) {
                acc[b][j] += xv.x * wB[j].x;
                acc[b][j] += xv.y * wB[j].y;
                acc[b][j] += xv.z * wB[j].z;
                acc[b][j] += xv.w * wB[j].w;
            }
        }
        __syncthreads();  // staging had the whole FMA phase to land: drain ~free
    }

    // ---- cross-lane reduction via padded LDS transpose, 2 passes (2 j's each)
#pragma unroll 1
    for (int pass = 0; pass < 2; ++pass) {
        if (pass) __syncthreads();
#pragma unroll
        for (int b = 0; b < 16; ++b)
#pragma unroll
            for (int jj = 0; jj < 2; ++jj)
                lds[(wv * 32 + b * 2 + jj) * 68 + lane] = acc[b][pass * 2 + jj];
        __syncthreads();
        if (tid < 256) {
            const float4* row = (const float4*)(lds + tid * 68);
            float sum = 0.f;
#pragma unroll
            for (int l = 0; l < 16; ++l) {
                const float4 v = row[l];
                sum += v.x + v.y + v.z + v.w;
            }
            const int wv2 = tid >> 5, r = tid & 31;
            const int b = r >> 1, jj = r & 1;
            const int o = ot * 32 + wv2 * 4 + pass * 2 + jj;
            atomicAdd(out + b * COUT_ + o, sum);
        }
    }
}

extern "C" void kernel_launch(void* const* d_in, const int* in_sizes, int n_in,
                              void* d_out, int out_size, void* d_ws, size_t ws_size,
                              hipStream_t stream) {
    const float* x    = (const float*)d_in[0];   // [16,128,4096]
    const float* wgt  = (const float*)d_in[1];   // [128,128,4096]
    const float* bias = (const float*)d_in[2];   // [128]
    float* out = (float*)d_out;                  // [16,128,1]
    (void)in_sizes; (void)n_in; (void)d_ws; (void)ws_size; (void)out_size;

    init_out_kernel<<<8, 256, 0, stream>>>(bias, out);
    conv_fft_dot_kernel<<<512, 512, 0, stream>>>(x, wgt, out);
}

// Round 3
// 467.105 us; speedup vs baseline: 1.1458x; 1.0659x over previous
//
#include <hip/hip_runtime.h>

// Conv1dFFTInt8: B=16, CIN=128, COUT=128, L=4096, out_size==1.
// Identity: ifft(sum_l X[l]W[l])[0] = sum_n x[n] * w[(L-n) mod L]  (real inputs)
// => out[b,o] = bias[o] + sum_i sum_m w[o,i,m] * x[b,i,(L-m)&(L-1)]
//
// Roofline: weight 268 MB read once (HBM) + x ~L2/L3-side => ~45-55 us.
// Round-2 failure: __launch_bounds__(512,4) capped VGPR at 64 (hipcc's
// occupancy targeting is 2x the documented waves/EU formula), forcing the
// 64-float accumulator into scratch: 690 MB WRITE_SIZE of pure spill.
// LDS (69.6 KB -> 2 blocks/CU = 4 waves/EU) is the real occupancy limit and
// only needs VGPR<=128. Fix: __launch_bounds__(512,1); allocator takes the
// ~120 VGPRs it needs, occupancy unchanged, spill gone.

constexpr int LEN   = 4096;
constexpr int CIN_  = 128;
constexpr int COUT_ = 128;
constexpr int BATCH = 16;

__global__ void init_out_kernel(const float* __restrict__ bias, float* __restrict__ out) {
    int t = blockIdx.x * 256 + threadIdx.x;
    if (t < BATCH * COUT_) out[t] = bias[t & (COUT_ - 1)];
}

// Async 4B global->LDS. LDS dest is wave-uniform base; HW writes base+lane*4.
// The index reversal lives in the per-lane GLOBAL address; LDS stays linear.
__device__ __forceinline__ void gload_lds4(const float* g, float* l) {
    __builtin_amdgcn_global_load_lds(
        (const __attribute__((address_space(1))) unsigned int*)g,
        (__attribute__((address_space(3))) unsigned int*)l, 4, 0, 0);
}

// Wave wv stages batches {2wv, 2wv+1}: lds[b][mm] = x[b,ci,(LEN-m0-mm)&4095], mm in [0,512)
__device__ __forceinline__ void stage_chunk(const float* __restrict__ x, float* dst_base,
                                            int ci, int m0, int wv, int lane) {
#pragma unroll
    for (int bb = 0; bb < 2; ++bb) {
        const int b = 2 * wv + bb;
        const float* xc = x + ((b * CIN_ + ci) << 12);
        float* dstb = dst_base + (b << 9);
#pragma unroll
        for (int t = 0; t < 8; ++t) {
            const int n = (LEN - m0 - (t << 6) - lane) & (LEN - 1);  // reversed source
            gload_lds4(xc + n, dstb + (t << 6));
        }
    }
}

// Block: 512 threads = 8 waves, each wave 4 o-rows (32 per block), ONE input
// channel. 8 K-chunks of 512. Grid = 4 o-tiles * 128 channels = 512 blocks.
// bk%8 == ci%8: the 4 channel-sharing blocks land on one XCD (x L2-hits).
__global__ __launch_bounds__(512, 1)
void conv_fft_dot_kernel(const float* __restrict__ x, const float* __restrict__ w,
                         float* __restrict__ out) {
    // 69,632 B: x double-buffer = 2*8192 floats (64 KB); reduce area 256 rows * 68.
    __shared__ float lds[17408];

    const int tid   = threadIdx.x;
    const int lane  = tid & 63;
    const int wv    = __builtin_amdgcn_readfirstlane(tid >> 6);
    const int bk    = blockIdx.x;
    const int ot    = bk >> 7;     // 0..3
    const int ci    = bk & 127;    // input channel
    const int obase = ot * 32 + wv * 4;

    float acc[16][4];
#pragma unroll
    for (int b = 0; b < 16; ++b)
#pragma unroll
        for (int j = 0; j < 4; ++j) acc[b][j] = 0.f;

    stage_chunk(x, lds, ci, 0, wv, lane);
    __syncthreads();

#pragma unroll 1
    for (int q = 0; q < 8; ++q) {
        const int m0 = q << 9;
        const float4* __restrict__ xb = (const float4*)(lds + ((q & 1) << 13));

        // ---- weight stream first (oldest in vmcnt queue): 8 dwordx4 / lane
        float4 wA[4], wB[4];
#pragma unroll
        for (int j = 0; j < 4; ++j) {
            const float4* wp = (const float4*)(w + (((obase + j) * CIN_ + ci) << 12) + m0);
            wA[j] = wp[lane];
            wB[j] = wp[64 + lane];
        }

        // ---- issue next chunk's x staging; completes under the FMAs
        if (q < 7)
            stage_chunk(x, lds + (((q + 1) & 1) << 13), ci, (q + 1) << 9, wv, lane);

        // ---- compute: 16 FMAs per ds_read_b128
#pragma unroll
        for (int b = 0; b < 16; ++b) {
            const float4 xv = xb[(b << 7) + lane];
#pragma unroll
            for (int j = 0; j < 4; ++j) {
                acc[b][j] += xv.x * wA[j].x;
                acc[b][j] += xv.y * wA[j].y;
                acc[b][j] += xv.z * wA[j].z;
                acc[b][j] += xv.w * wA[j].w;
            }
        }
#pragma unroll
        for (int b = 0; b < 16; ++b) {
            const float4 xv = xb[(b << 7) + 64 + lane];
#pragma unroll
            for (int j = 0; j < 4; ++j) {
                acc[b][j] += xv.x * wB[j].x;
                acc[b][j] += xv.y * wB[j].y;
                acc[b][j] += xv.z * wB[j].z;
                acc[b][j] += xv.w * wB[j].w;
            }
        }
        __syncthreads();  // staging had the whole FMA phase to land: drain ~free
    }

    // ---- cross-lane reduction via padded LDS transpose, 2 passes (2 j's each)
#pragma unroll 1
    for (int pass = 0; pass < 2; ++pass) {
        if (pass) __syncthreads();
#pragma unroll
        for (int b = 0; b < 16; ++b)
#pragma unroll
            for (int jj = 0; jj < 2; ++jj)
                lds[(wv * 32 + b * 2 + jj) * 68 + lane] = acc[b][pass * 2 + jj];
        __syncthreads();
        if (tid < 256) {
            const float4* row = (const float4*)(lds + tid * 68);
            float sum = 0.f;
#pragma unroll
            for (int l = 0; l < 16; ++l) {
                const float4 v = row[l];
                sum += v.x + v.y + v.z + v.w;
            }
            const int wv2 = tid >> 5, r = tid & 31;
            const int b = r >> 1, jj = r & 1;
            const int o = ot * 32 + wv2 * 4 + pass * 2 + jj;
            atomicAdd(out + b * COUT_ + o, sum);
        }
    }
}

extern "C" void kernel_launch(void* const* d_in, const int* in_sizes, int n_in,
                              void* d_out, int out_size, void* d_ws, size_t ws_size,
                              hipStream_t stream) {
    const float* x    = (const float*)d_in[0];   // [16,128,4096]
    const float* wgt  = (const float*)d_in[1];   // [128,128,4096]
    const float* bias = (const float*)d_in[2];   // [128]
    float* out = (float*)d_out;                  // [16,128,1]
    (void)in_sizes; (void)n_in; (void)d_ws; (void)ws_size; (void)out_size;

    init_out_kernel<<<8, 256, 0, stream>>>(bias, out);
    conv_fft_dot_kernel<<<512, 512, 0, stream>>>(x, wgt, out);
}

// Round 4
// 403.911 us; speedup vs baseline: 1.3251x; 1.1565x over previous
//
#include <hip/hip_runtime.h>

// Conv1dFFTInt8: B=16, CIN=128, COUT=128, L=4096, out_size==1.
// Identity: ifft(sum_l X[l]W[l])[0] = sum_n x[n] * w[(L-n) mod L]  (real inputs)
// => out[b,o] = bias[o] + sum_i sum_m w[o,i,m] * x[b,i,(L-m)&(L-1)]
//
// Roofline: weight 268 MB read once (HBM) + x L2/L3-side => ~45-55 us.
// Rounds 1-3 failure (rule #20): the epilogue's `#pragma unroll 1` pass-loop
// indexed acc[b][pass*2+jj] with runtime 'pass' -> the WHOLE acc array was
// allocated in scratch -> 537+ MB of spill traffic in the main loop and
// VGPR_Count=64 (acc not in registers at all). launch_bounds was never the
// problem. Fix: fully-static epilogue (unrolled pass loop); acc stays in VGPRs.

constexpr int LEN   = 4096;
constexpr int CIN_  = 128;
constexpr int COUT_ = 128;
constexpr int BATCH = 16;

__global__ void init_out_kernel(const float* __restrict__ bias, float* __restrict__ out) {
    int t = blockIdx.x * 256 + threadIdx.x;
    if (t < BATCH * COUT_) out[t] = bias[t & (COUT_ - 1)];
}

// Async 4B global->LDS. LDS dest is wave-uniform base; HW writes base+lane*4.
// The index reversal lives in the per-lane GLOBAL address; LDS stays linear.
__device__ __forceinline__ void gload_lds4(const float* g, float* l) {
    __builtin_amdgcn_global_load_lds(
        (const __attribute__((address_space(1))) unsigned int*)g,
        (__attribute__((address_space(3))) unsigned int*)l, 4, 0, 0);
}

// Wave wv stages batches {2wv, 2wv+1}: lds[b][mm] = x[b,ci,(LEN-m0-mm)&4095], mm in [0,512)
__device__ __forceinline__ void stage_chunk(const float* __restrict__ x, float* dst_base,
                                            int ci, int m0, int wv, int lane) {
#pragma unroll
    for (int bb = 0; bb < 2; ++bb) {
        const int b = 2 * wv + bb;
        const float* xc = x + ((b * CIN_ + ci) << 12);
        float* dstb = dst_base + (b << 9);
#pragma unroll
        for (int t = 0; t < 8; ++t) {
            const int n = (LEN - m0 - (t << 6) - lane) & (LEN - 1);  // reversed source
            gload_lds4(xc + n, dstb + (t << 6));
        }
    }
}

// Block: 512 threads = 8 waves, each wave 4 o-rows (32 per block), ONE input
// channel. 8 K-chunks of 512. Grid = 4 o-tiles * 128 channels = 512 blocks.
// bk%8 == ci%8: the 4 channel-sharing blocks land on one XCD (x L2-hits).
__global__ __launch_bounds__(512, 1)
void conv_fft_dot_kernel(const float* __restrict__ x, const float* __restrict__ w,
                         float* __restrict__ out) {
    // 69,632 B: x double-buffer = 2*8192 floats (64 KB); reduce area 256 rows * 68.
    __shared__ float lds[17408];

    const int tid   = threadIdx.x;
    const int lane  = tid & 63;
    const int wv    = __builtin_amdgcn_readfirstlane(tid >> 6);
    const int bk    = blockIdx.x;
    const int ot    = bk >> 7;     // 0..3
    const int ci    = bk & 127;    // input channel
    const int obase = ot * 32 + wv * 4;

    float acc[16][4];
#pragma unroll
    for (int b = 0; b < 16; ++b)
#pragma unroll
        for (int j = 0; j < 4; ++j) acc[b][j] = 0.f;

    stage_chunk(x, lds, ci, 0, wv, lane);
    __syncthreads();

#pragma unroll 1
    for (int q = 0; q < 8; ++q) {
        const int m0 = q << 9;
        const float4* __restrict__ xb = (const float4*)(lds + ((q & 1) << 13));

        // ---- weight stream first (oldest in vmcnt queue): 8 dwordx4 / lane
        float4 wA[4], wB[4];
#pragma unroll
        for (int j = 0; j < 4; ++j) {
            const float4* wp = (const float4*)(w + (((obase + j) * CIN_ + ci) << 12) + m0);
            wA[j] = wp[lane];
            wB[j] = wp[64 + lane];
        }

        // ---- issue next chunk's x staging; completes under the FMAs
        if (q < 7)
            stage_chunk(x, lds + (((q + 1) & 1) << 13), ci, (q + 1) << 9, wv, lane);

        // ---- compute: 16 FMAs per ds_read_b128
#pragma unroll
        for (int b = 0; b < 16; ++b) {
            const float4 xv = xb[(b << 7) + lane];
#pragma unroll
            for (int j = 0; j < 4; ++j) {
                acc[b][j] += xv.x * wA[j].x;
                acc[b][j] += xv.y * wA[j].y;
                acc[b][j] += xv.z * wA[j].z;
                acc[b][j] += xv.w * wA[j].w;
            }
        }
#pragma unroll
        for (int b = 0; b < 16; ++b) {
            const float4 xv = xb[(b << 7) + 64 + lane];
#pragma unroll
            for (int j = 0; j < 4; ++j) {
                acc[b][j] += xv.x * wB[j].x;
                acc[b][j] += xv.y * wB[j].y;
                acc[b][j] += xv.z * wB[j].z;
                acc[b][j] += xv.w * wB[j].w;
            }
        }
        __syncthreads();  // staging had the whole FMA phase to land: drain ~free
    }

    // ---- cross-lane reduction via padded LDS transpose.
    // FULLY STATIC (rule #20): the pass loop is unrolled so every acc index is
    // a compile-time constant; acc[] must stay in VGPRs.
#pragma unroll
    for (int pass = 0; pass < 2; ++pass) {
        if (pass) __syncthreads();
#pragma unroll
        for (int b = 0; b < 16; ++b) {
            lds[(wv * 32 + b * 2 + 0) * 68 + lane] = acc[b][pass * 2 + 0];
            lds[(wv * 32 + b * 2 + 1) * 68 + lane] = acc[b][pass * 2 + 1];
        }
        __syncthreads();
        if (tid < 256) {
            const float4* row = (const float4*)(lds + tid * 68);
            float sum = 0.f;
#pragma unroll
            for (int l = 0; l < 16; ++l) {
                const float4 v = row[l];
                sum += v.x + v.y + v.z + v.w;
            }
            const int wv2 = tid >> 5, r = tid & 31;
            const int b = r >> 1, jj = r & 1;
            const int o = ot * 32 + wv2 * 4 + pass * 2 + jj;
            atomicAdd(out + b * COUT_ + o, sum);
        }
    }
}

extern "C" void kernel_launch(void* const* d_in, const int* in_sizes, int n_in,
                              void* d_out, int out_size, void* d_ws, size_t ws_size,
                              hipStream_t stream) {
    const float* x    = (const float*)d_in[0];   // [16,128,4096]
    const float* wgt  = (const float*)d_in[1];   // [128,128,4096]
    const float* bias = (const float*)d_in[2];   // [128]
    float* out = (float*)d_out;                  // [16,128,1]
    (void)in_sizes; (void)n_in; (void)d_ws; (void)ws_size; (void)out_size;

    init_out_kernel<<<8, 256, 0, stream>>>(bias, out);
    conv_fft_dot_kernel<<<512, 512, 0, stream>>>(x, wgt, out);
}

// Round 5
// 393.581 us; speedup vs baseline: 1.3598x; 1.0262x over previous
//
#include <hip/hip_runtime.h>

// Conv1dFFTInt8: B=16, CIN=128, COUT=128, L=4096, out_size==1.
// Identity: ifft(sum_l X[l]W[l])[0] = sum_n x[n] * w[(L-n) mod L]  (real inputs)
// => out[b,o] = bias[o] + sum_i sum_m w[o,i,m] * x[b,i,(L-m)&(L-1)]
//
// Roofline: 268 MB weights (once, HBM) + 32 MB x (L3) => ~48 us @ 6.3 TB/s.
// Round-4 est. ~74 us: barrier-locked waves oscillate between a weight-load
// burst (HBM queued, VALU idle) and a compute phase (HBM idle) -> ~60% BW.
// This version: T3/T4 pipeline. Half-q weight prefetch into alternating
// statically-named registers + counted-vmcnt barrier (vmcnt(2) keeps the 2
// cross-barrier weight loads in flight; drains the 16 staging gload_lds,
// which sched_barrier(0) pins to issue BEFORE the weight reloads).
// o-tile 16 (acc[16][2]=32 VGPR, ~75 total) for register safety.

constexpr int LEN   = 4096;
constexpr int CIN_  = 128;
constexpr int COUT_ = 128;
constexpr int BATCH = 16;

__global__ void init_out_kernel(const float* __restrict__ bias, float* __restrict__ out) {
    int t = blockIdx.x * 256 + threadIdx.x;
    if (t < BATCH * COUT_) out[t] = bias[t & (COUT_ - 1)];
}

// Async 4B global->LDS. LDS dest is wave-uniform base; HW writes base+lane*4.
// The index reversal lives in the per-lane GLOBAL address; LDS stays linear.
__device__ __forceinline__ void gload_lds4(const float* g, float* l) {
    __builtin_amdgcn_global_load_lds(
        (const __attribute__((address_space(1))) unsigned int*)g,
        (__attribute__((address_space(3))) unsigned int*)l, 4, 0, 0);
}

// Wave wv stages batches {2wv, 2wv+1}: lds[b][mm] = x[b,ci,(LEN-m0-mm)&4095], mm in [0,512)
__device__ __forceinline__ void stage_chunk(const float* __restrict__ x, float* dst_base,
                                            int ci, int m0, int wv, int lane) {
#pragma unroll
    for (int bb = 0; bb < 2; ++bb) {
        const int b = 2 * wv + bb;
        const float* xc = x + ((b * CIN_ + ci) << 12);
        float* dstb = dst_base + (b << 9);
#pragma unroll
        for (int t = 0; t < 8; ++t) {
            const int n = (LEN - m0 - (t << 6) - lane) & (LEN - 1);  // reversed source
            gload_lds4(xc + n, dstb + (t << 6));
        }
    }
}

// Block: 512 threads = 8 waves, each wave 2 o-rows (16 per block), ONE input
// channel. 8 K-chunks of 512, each split in 2 half-phases. Grid = 8 o-tiles *
// 128 channels = 1024 blocks. bk%8 == ci%8: channel-sharing blocks co-XCD.
// __launch_bounds__(512,2): empirical hipcc cap = 256/arg = 128 VGPR.
__global__ __launch_bounds__(512, 2)
void conv_fft_dot_kernel(const float* __restrict__ x, const float* __restrict__ w,
                         float* __restrict__ out) {
    // 69,632 B: x double-buffer = 2*8192 floats (64 KB); reduce area 256 rows * 68.
    __shared__ float lds[17408];

    const int tid   = threadIdx.x;
    const int lane  = tid & 63;
    const int wv    = __builtin_amdgcn_readfirstlane(tid >> 6);
    const int bk    = blockIdx.x;
    const int ot    = bk >> 7;     // 0..7
    const int ci    = bk & 127;    // input channel
    const int obase = ot * 16 + wv * 2;

    // per-wave uniform weight-row bases (live in SGPRs via readfirstlane'd wv)
    const float* wr0 = w + (((obase + 0) * CIN_ + ci) << 12);
    const float* wr1 = w + (((obase + 1) * CIN_ + ci) << 12);

    float acc[16][2];
#pragma unroll
    for (int b = 0; b < 16; ++b) { acc[b][0] = 0.f; acc[b][1] = 0.f; }

    // ---- prologue: stage chunk 0, then half-0 weights (the 2 NEWEST vm ops)
    stage_chunk(x, lds, ci, 0, wv, lane);
    __builtin_amdgcn_sched_barrier(0);           // staging strictly before wa
    float4 wa0 = ((const float4*)wr0)[lane];
    float4 wa1 = ((const float4*)wr1)[lane];
    asm volatile("s_waitcnt vmcnt(2)" ::: "memory");  // drain staging, keep wa
    __builtin_amdgcn_s_barrier();
    __builtin_amdgcn_sched_barrier(0);

#pragma unroll 1
    for (int q = 0; q < 8; ++q) {
        const int m0 = q << 9;
        const float4* __restrict__ xb = (const float4*)(lds + ((q & 1) << 13));

        // half-B weights: issued now, consumed later this q (never cross barrier)
        float4 wb0 = ((const float4*)(wr0 + m0 + 256))[lane];
        float4 wb1 = ((const float4*)(wr1 + m0 + 256))[lane];

        // next-chunk staging: must issue BEFORE the wa reloads (vmcnt(2) invariant)
        if (q < 7)
            stage_chunk(x, lds + (((q + 1) & 1) << 13), ci, (q + 1) << 9, wv, lane);

        // ---- compute half A (wa* issued one half-phase ago, across the barrier)
#pragma unroll
        for (int b = 0; b < 16; ++b) {
            const float4 xv = xb[(b << 7) + lane];
            acc[b][0] += xv.x * wa0.x; acc[b][0] += xv.y * wa0.y;
            acc[b][0] += xv.z * wa0.z; acc[b][0] += xv.w * wa0.w;
            acc[b][1] += xv.x * wa1.x; acc[b][1] += xv.y * wa1.y;
            acc[b][1] += xv.z * wa1.z; acc[b][1] += xv.w * wa1.w;
        }

        __builtin_amdgcn_sched_barrier(0);  // fence: staging stays before wa reloads

        // next q's half-A weights: the only loads that cross the barrier
        if (q < 7) {
            wa0 = ((const float4*)(wr0 + m0 + 512))[lane];
            wa1 = ((const float4*)(wr1 + m0 + 512))[lane];
        }

        // ---- compute half B
#pragma unroll
        for (int b = 0; b < 16; ++b) {
            const float4 xv = xb[(b << 7) + 64 + lane];
            acc[b][0] += xv.x * wb0.x; acc[b][0] += xv.y * wb0.y;
            acc[b][0] += xv.z * wb0.z; acc[b][0] += xv.w * wb0.w;
            acc[b][1] += xv.x * wb1.x; acc[b][1] += xv.y * wb1.y;
            acc[b][1] += xv.z * wb1.z; acc[b][1] += xv.w * wb1.w;
        }

        if (q < 7) {
            // counted barrier: drain staging (older), keep the 2 wa loads in flight
            asm volatile("s_waitcnt vmcnt(2)" ::: "memory");
            __builtin_amdgcn_s_barrier();
            __builtin_amdgcn_sched_barrier(0);
        }
    }

    // ---- cross-lane reduction via padded LDS transpose (fully static, rule #20)
    __syncthreads();   // full drain; also all waves done reading x buffers
#pragma unroll
    for (int b = 0; b < 16; ++b) {
        lds[(wv * 32 + b * 2 + 0) * 68 + lane] = acc[b][0];
        lds[(wv * 32 + b * 2 + 1) * 68 + lane] = acc[b][1];
    }
    __syncthreads();
    if (tid < 256) {
        const float4* row = (const float4*)(lds + tid * 68);  // 272 B = 17*16: aligned
        float sum = 0.f;
#pragma unroll
        for (int l = 0; l < 16; ++l) {
            const float4 v = row[l];
            sum += v.x + v.y + v.z + v.w;
        }
        const int wv2 = tid >> 5, r = tid & 31;
        const int b = r >> 1, jj = r & 1;
        const int o = ot * 16 + wv2 * 2 + jj;
        atomicAdd(out + b * COUT_ + o, sum);
    }
}

extern "C" void kernel_launch(void* const* d_in, const int* in_sizes, int n_in,
                              void* d_out, int out_size, void* d_ws, size_t ws_size,
                              hipStream_t stream) {
    const float* x    = (const float*)d_in[0];   // [16,128,4096]
    const float* wgt  = (const float*)d_in[1];   // [128,128,4096]
    const float* bias = (const float*)d_in[2];   // [128]
    float* out = (float*)d_out;                  // [16,128,1]
    (void)in_sizes; (void)n_in; (void)d_ws; (void)ws_size; (void)out_size;

    init_out_kernel<<<8, 256, 0, stream>>>(bias, out);
    conv_fft_dot_kernel<<<1024, 512, 0, stream>>>(x, wgt, out);
}

// Round 6
// 382.261 us; speedup vs baseline: 1.4001x; 1.0296x over previous
//
#include <hip/hip_runtime.h>

// Conv1dFFTInt8: B=16, CIN=128, COUT=128, L=4096, out_size==1.
// Identity: ifft(sum_l X[l]W[l])[0] = sum_n x[n] * w[(L-n) mod L]  (real inputs)
// => out[b,o] = bias[o] + sum_i sum_m w[o,i,m] * x[b,i,(L-m)&(L-1)]
//
// Roofline: 268 MB weights (once, HBM) + 32 MB x => ~48 us @ 6.3 TB/s.
// Round 5 (~64 us): o-tile 16, counted-vmcnt pipeline. This round:
//  * o-tile 32 (round-4's proven register shape: acc[16][4]+w[8], static
//    epilogue, ~112 VGPR under the 128 cap) + the round-5 pipeline -> grid
//    512 = one pass, x re-staged 4x not 8x.
//  * non-temporal weight loads: weights are single-use; keep them out of L2
//    so the per-XCD x working set (16ci*16b*16KB = 4MB = L2 size) stays
//    resident across its 4 ot-sibling re-reads.

constexpr int LEN   = 4096;
constexpr int CIN_  = 128;
constexpr int COUT_ = 128;
constexpr int BATCH = 16;

typedef float f32x4 __attribute__((ext_vector_type(4)));

__global__ void init_out_kernel(const float* __restrict__ bias, float* __restrict__ out) {
    int t = blockIdx.x * 256 + threadIdx.x;
    if (t < BATCH * COUT_) out[t] = bias[t & (COUT_ - 1)];
}

// Non-temporal 16B weight load: read-once stream, don't allocate in L2.
__device__ __forceinline__ f32x4 ntload4(const float* p) {
    return __builtin_nontemporal_load((const f32x4*)p);
}

// Async 4B global->LDS. LDS dest is wave-uniform base; HW writes base+lane*4.
// The index reversal lives in the per-lane GLOBAL address; LDS stays linear.
__device__ __forceinline__ void gload_lds4(const float* g, float* l) {
    __builtin_amdgcn_global_load_lds(
        (const __attribute__((address_space(1))) unsigned int*)g,
        (__attribute__((address_space(3))) unsigned int*)l, 4, 0, 0);
}

// Wave wv stages batches {2wv, 2wv+1}: lds[b][mm] = x[b,ci,(LEN-m0-mm)&4095], mm in [0,512)
__device__ __forceinline__ void stage_chunk(const float* __restrict__ x, float* dst_base,
                                            int ci, int m0, int wv, int lane) {
#pragma unroll
    for (int bb = 0; bb < 2; ++bb) {
        const int b = 2 * wv + bb;
        const float* xc = x + ((b * CIN_ + ci) << 12);
        float* dstb = dst_base + (b << 9);
#pragma unroll
        for (int t = 0; t < 8; ++t) {
            const int n = (LEN - m0 - (t << 6) - lane) & (LEN - 1);  // reversed source
            gload_lds4(xc + n, dstb + (t << 6));
        }
    }
}

// Block: 512 threads = 8 waves, each wave 4 o-rows (32 per block), ONE input
// channel. 8 K-chunks of 512, each split in 2 half-phases. Grid = 4 o-tiles *
// 128 channels = 512 blocks = single grid pass at 2 blocks/CU.
// bk%8 == ci%8: the 4 channel-sharing blocks land on one XCD (x L2-hits).
// __launch_bounds__(512,2): empirical hipcc cap = 256/arg = 128 VGPR
// (= exactly the LDS-bound 4 waves/SIMD budget).
__global__ __launch_bounds__(512, 2)
void conv_fft_dot_kernel(const float* __restrict__ x, const float* __restrict__ w,
                         float* __restrict__ out) {
    // 69,632 B: x double-buffer = 2*8192 floats (64 KB); reduce area 256 rows * 68.
    __shared__ float lds[17408];

    const int tid   = threadIdx.x;
    const int lane  = tid & 63;
    const int wv    = __builtin_amdgcn_readfirstlane(tid >> 6);
    const int bk    = blockIdx.x;
    const int ot    = bk >> 7;     // 0..3
    const int ci    = bk & 127;    // input channel
    const int obase = ot * 32 + wv * 4;

    const float* wr0 = w + (((obase + 0) * CIN_ + ci) << 12);
    const float* wr1 = w + (((obase + 1) * CIN_ + ci) << 12);
    const float* wr2 = w + (((obase + 2) * CIN_ + ci) << 12);
    const float* wr3 = w + (((obase + 3) * CIN_ + ci) << 12);
    const int lo16 = lane << 2;   // float offset of this lane's float4

    float acc[16][4];
#pragma unroll
    for (int b = 0; b < 16; ++b)
#pragma unroll
        for (int j = 0; j < 4; ++j) acc[b][j] = 0.f;

    // ---- prologue: stage chunk 0, then half-0 weights (the 4 NEWEST vm ops)
    stage_chunk(x, lds, ci, 0, wv, lane);
    __builtin_amdgcn_sched_barrier(0);           // staging strictly before wa
    f32x4 wa[4];
    wa[0] = ntload4(wr0 + lo16); wa[1] = ntload4(wr1 + lo16);
    wa[2] = ntload4(wr2 + lo16); wa[3] = ntload4(wr3 + lo16);
    asm volatile("s_waitcnt vmcnt(4)" ::: "memory");  // drain staging, keep wa
    __builtin_amdgcn_s_barrier();
    __builtin_amdgcn_sched_barrier(0);

#pragma unroll 1
    for (int q = 0; q < 8; ++q) {
        const int m0 = q << 9;
        const float4* __restrict__ xb = (const float4*)(lds + ((q & 1) << 13));

        // half-B weights: issued now, consumed later this q (never cross barrier)
        f32x4 wb[4];
        wb[0] = ntload4(wr0 + m0 + 256 + lo16);
        wb[1] = ntload4(wr1 + m0 + 256 + lo16);
        wb[2] = ntload4(wr2 + m0 + 256 + lo16);
        wb[3] = ntload4(wr3 + m0 + 256 + lo16);

        // next-chunk staging: must issue BEFORE the wa reloads (vmcnt(4) invariant)
        if (q < 7)
            stage_chunk(x, lds + (((q + 1) & 1) << 13), ci, (q + 1) << 9, wv, lane);

        // ---- compute half A (wa issued one half-phase ago, across the barrier)
#pragma unroll
        for (int b = 0; b < 16; ++b) {
            const float4 xv = xb[(b << 7) + lane];
#pragma unroll
            for (int j = 0; j < 4; ++j) {
                acc[b][j] += xv.x * wa[j].x;
                acc[b][j] += xv.y * wa[j].y;
                acc[b][j] += xv.z * wa[j].z;
                acc[b][j] += xv.w * wa[j].w;
            }
        }

        __builtin_amdgcn_sched_barrier(0);  // fence: staging stays before wa reloads

        // next q's half-A weights: the only loads that cross the barrier
        if (q < 7) {
            wa[0] = ntload4(wr0 + m0 + 512 + lo16);
            wa[1] = ntload4(wr1 + m0 + 512 + lo16);
            wa[2] = ntload4(wr2 + m0 + 512 + lo16);
            wa[3] = ntload4(wr3 + m0 + 512 + lo16);
        }

        // ---- compute half B
#pragma unroll
        for (int b = 0; b < 16; ++b) {
            const float4 xv = xb[(b << 7) + 64 + lane];
#pragma unroll
            for (int j = 0; j < 4; ++j) {
                acc[b][j] += xv.x * wb[j].x;
                acc[b][j] += xv.y * wb[j].y;
                acc[b][j] += xv.z * wb[j].z;
                acc[b][j] += xv.w * wb[j].w;
            }
        }

        if (q < 7) {
            // counted barrier: drain staging (older), keep the 4 wa loads in flight
            asm volatile("s_waitcnt vmcnt(4)" ::: "memory");
            __builtin_amdgcn_s_barrier();
            __builtin_amdgcn_sched_barrier(0);
        }
    }

    // ---- cross-lane reduction via padded LDS transpose (fully static, rule #20)
    __syncthreads();   // full drain; all waves done reading x buffers
#pragma unroll
    for (int pass = 0; pass < 2; ++pass) {
        if (pass) __syncthreads();
#pragma unroll
        for (int b = 0; b < 16; ++b) {
            lds[(wv * 32 + b * 2 + 0) * 68 + lane] = acc[b][pass * 2 + 0];
            lds[(wv * 32 + b * 2 + 1) * 68 + lane] = acc[b][pass * 2 + 1];
        }
        __syncthreads();
        if (tid < 256) {
            const float4* row = (const float4*)(lds + tid * 68);  // 272 B = 17*16: aligned
            float sum = 0.f;
#pragma unroll
            for (int l = 0; l < 16; ++l) {
                const float4 v = row[l];
                sum += v.x + v.y + v.z + v.w;
            }
            const int wv2 = tid >> 5, r = tid & 31;
            const int b = r >> 1, jj = r & 1;
            const int o = ot * 32 + wv2 * 4 + pass * 2 + jj;
            atomicAdd(out + b * COUT_ + o, sum);
        }
    }
}

extern "C" void kernel_launch(void* const* d_in, const int* in_sizes, int n_in,
                              void* d_out, int out_size, void* d_ws, size_t ws_size,
                              hipStream_t stream) {
    const float* x    = (const float*)d_in[0];   // [16,128,4096]
    const float* wgt  = (const float*)d_in[1];   // [128,128,4096]
    const float* bias = (const float*)d_in[2];   // [128]
    float* out = (float*)d_out;                  // [16,128,1]
    (void)in_sizes; (void)n_in; (void)d_ws; (void)ws_size; (void)out_size;

    init_out_kernel<<<8, 256, 0, stream>>>(bias, out);
    conv_fft_dot_kernel<<<512, 512, 0, stream>>>(x, wgt, out);
}